// Round 8
// baseline (264.732 us; speedup 1.0000x reference)
//
#include <hip/hip_runtime.h>

typedef __attribute__((ext_vector_type(8))) short short8;
typedef __attribute__((ext_vector_type(4))) short short4v;
typedef __attribute__((ext_vector_type(4))) float float4v;

#define NPIX_HID 8388608   // 8*64*128*128
#define PST 132            // shorts per px row in LDS (pitch 66 dwords: measured 0 conflicts w/ b64)
#define ROWPITCH (66 * PST)

__device__ __forceinline__ short f2bf(float f) {
    union { float f; unsigned u; } v; v.f = f;
    unsigned r = (v.u + 0x7FFFu + ((v.u >> 16) & 1u)) >> 16;
    return (short)r;
}

__device__ __forceinline__ float sigmoidf_(float v) { return 1.f / (1.f + __expf(-v)); }
__device__ __forceinline__ float tanhf_(float v)    { return 2.f / (1.f + __expf(-2.f * v)) - 1.f; }

// Pack W[co][ci][ky][kx] fp32 -> Aprep[kk][ci/8][co][ci%8] bf16 (MFMA A-frag order).
__global__ void wprep(const float* __restrict__ W, short* __restrict__ A) {
    int tid = blockIdx.x * 256 + threadIdx.x;
    if (tid >= 9 * 16 * 256 * 8) return;
    int j   = tid & 7;
    int co  = (tid >> 3) & 255;
    int cig = (tid >> 11) & 15;
    int kk  = tid >> 15;
    int ci  = cig * 8 + j;
    A[tid] = f2bf(W[co * 1152 + ci * 9 + kk]);
}

// ---- prologue staging (3 rows, 3168 items), 2-deep pipelined, ring slots 3,0,1 ----
#define PRO_LOAD(P, II)                                                       \
  {                                                                           \
    const int i_ = (II);                                                      \
    P##_act = (i_ < 3168);                                                    \
    const int px_ = i_ % 66;                                                  \
    const int ro_ = i_ / 66;                                                  \
    P##_oct = ro_ & 15;                                                       \
    P##_row = ro_ >> 4;                                                       \
    const int ys_ = y0 + P##_row - 1;                                         \
    const int xs_ = x0 + px_ - 1;                                             \
    P##_px = px_;                                                             \
    P##_ok = P##_act & ((unsigned)ys_ < 128u) & ((unsigned)xs_ < 128u);       \
    const float* src_ = (P##_oct < 8) ? x : ph;                               \
    const float* sp_ = src_ + (P##_ok ?                                       \
        (((b * 64 + (P##_oct & 7) * 8) * 128 + ys_) * 128 + xs_) : 0);        \
    P##_v[0]=sp_[0]; P##_v[1]=sp_[16384]; P##_v[2]=sp_[2*16384];              \
    P##_v[3]=sp_[3*16384]; P##_v[4]=sp_[4*16384]; P##_v[5]=sp_[5*16384];      \
    P##_v[6]=sp_[6*16384]; P##_v[7]=sp_[7*16384];                             \
  }

#define PRO_PROC(P)                                                           \
  if (P##_act) {                                                              \
    short4v lo_={0,0,0,0}, hi_={0,0,0,0};                                     \
    if (P##_ok) {                                                             \
      lo_[0]=f2bf(P##_v[0]); lo_[1]=f2bf(P##_v[1]);                           \
      lo_[2]=f2bf(P##_v[2]); lo_[3]=f2bf(P##_v[3]);                           \
      hi_[0]=f2bf(P##_v[4]); hi_[1]=f2bf(P##_v[5]);                           \
      hi_[2]=f2bf(P##_v[6]); hi_[3]=f2bf(P##_v[7]);                           \
    }                                                                         \
    short* dst_ = &Bs[(((P##_row + 3) & 3) * 66 + P##_px) * PST + P##_oct * 8]; \
    *(short4v*)dst_ = lo_; *(short4v*)(dst_+4) = hi_;                         \
  }

// ---- per-iteration staging (1 row, 1056 items = 5 guarded slots/thread) ----
// Loads issued BEFORE the K-loop (latency hidden under MFMA); values held in
// regs; converted + written to ring slot AFTER the K-loop.
#define IST_LOAD(P, K)                                                        \
  {                                                                           \
    const int i_ = tid + (K) * 256;                                           \
    const int px_ = i_ % 66;                                                  \
    const int oct_ = (i_ / 66) & 15;                                          \
    const int xs_ = x0 + px_ - 1;                                             \
    const bool ok_ = (i_ < 1056) & ((unsigned)ysrc < 128u)                    \
                     & ((unsigned)xs_ < 128u);                                \
    const float* src_ = (oct_ < 8) ? x : ph;                                  \
    const float* sp_ = src_ + (ok_ ?                                          \
        (((b * 64 + (oct_ & 7) * 8) * 128 + ysrc) * 128 + xs_) : 0);          \
    P##_v[0]=sp_[0]; P##_v[1]=sp_[16384]; P##_v[2]=sp_[2*16384];              \
    P##_v[3]=sp_[3*16384]; P##_v[4]=sp_[4*16384]; P##_v[5]=sp_[5*16384];      \
    P##_v[6]=sp_[6*16384]; P##_v[7]=sp_[7*16384];                             \
  }

#define IST_WRITE(P, K)                                                       \
  {                                                                           \
    const int i_ = tid + (K) * 256;                                           \
    if (i_ < 1056) {                                                          \
      const int px_ = i_ % 66;                                                \
      const int oct_ = i_ / 66;                                               \
      const int xs_ = x0 + px_ - 1;                                           \
      const bool ok_ = ((unsigned)ysrc < 128u) & ((unsigned)xs_ < 128u);      \
      short4v lo_={0,0,0,0}, hi_={0,0,0,0};                                   \
      if (ok_) {                                                              \
        lo_[0]=f2bf(P##_v[0]); lo_[1]=f2bf(P##_v[1]);                         \
        lo_[2]=f2bf(P##_v[2]); lo_[3]=f2bf(P##_v[3]);                         \
        hi_[0]=f2bf(P##_v[4]); hi_[1]=f2bf(P##_v[5]);                         \
        hi_[2]=f2bf(P##_v[6]); hi_[3]=f2bf(P##_v[7]);                         \
      }                                                                       \
      short* dst_ = &Bs[(wslot * 66 + px_) * PST + oct_ * 8];                 \
      *(short4v*)dst_ = lo_; *(short4v*)(dst_+4) = hi_;                       \
    }                                                                         \
  }

// Ring-walk block: 4 output rows per block, 1 row/iteration, 4-slot LDS row ring
// (slot = input_row & 3). Staging of row y+2 overlaps the K-loop of row y.
// 512 blocks = 2/CU resident. K-loop = proven A/B dbuf (wraps into next iter).
__global__ __launch_bounds__(256, 2) void convlstm_main(
    const float* __restrict__ x, const float* __restrict__ ph,
    const float* __restrict__ pc, const short* __restrict__ aprep,
    const float* __restrict__ bg, float* __restrict__ out)
{
    __shared__ short Bs[4 * ROWPITCH];   // 69,696 B

    const int tid  = threadIdx.x;
    const int lane = tid & 63;
    const int wave = tid >> 6;
    const int l15  = lane & 15;
    const int quad = lane >> 4;

    const int t  = blockIdx.x;           // 512 blocks: 2 x-halves, 32 y-groups, 8 batch
    const int x0 = (t & 1) * 64;
    const int y0 = ((t >> 1) & 31) * 4;
    const int b  = t >> 6;

    // ---- prologue: stage input rows y0-1, y0, y0+1 into slots 3, 0, 1 ----
    {
        float pA_v[8]; int pA_px, pA_row, pA_oct; bool pA_ok, pA_act;
        float pB_v[8]; int pB_px, pB_row, pB_oct; bool pB_ok, pB_act;
        int ib = tid;
        PRO_LOAD(pA, ib);
#pragma unroll 1
        for (int it = 0; it < 12; it += 2) {
            PRO_LOAD(pB, ib + 256);
            PRO_PROC(pA);
            PRO_LOAD(pA, ib + 512);
            PRO_PROC(pB);
            ib += 512;
        }
        PRO_PROC(pA);   // round 12 (tid < 96)
    }
    __syncthreads();

    // ---- one-time K-state init (abuf/bfr wrap keeps it warm across iterations) ----
    const short* ap_base = aprep + quad * 2048 + (wave * 16 + l15) * 8;
    const short* ap = ap_base;
    short8 abuf[2][4];
#pragma unroll
    for (int mt = 0; mt < 4; ++mt) abuf[0][mt] = *(const short8*)(ap_base + mt * 512);

    const int lqoff = l15 * PST + quad * 8;
    const short* bb = &Bs[3 * ROWPITCH + lqoff];   // slot 3 = ky0 base of yy=0
    short8 bfr[2][4];
#pragma unroll
    for (int nt = 0; nt < 4; ++nt) {
        const short* bp = bb + nt * (16 * PST);
        short4v lo = *(const short4v*)bp;
        short4v hi = *(const short4v*)(bp + 4);
        bfr[0][nt] = __builtin_shufflevector(lo, hi, 0, 1, 2, 3, 4, 5, 6, 7);
    }

    float bgv[4][4];
#pragma unroll
    for (int g = 0; g < 4; ++g)
#pragma unroll
        for (int r = 0; r < 4; ++r)
            bgv[g][r] = bg[g * 64 + wave * 16 + quad * 4 + r];

#pragma unroll 1
    for (int yy = 0; yy < 4; ++yy) {
        const int ysrc  = y0 + yy + 2;        // input row staged this iteration
        const int wslot = (yy + 2) & 3;
        const short* bbnext = &Bs[(yy & 3) * ROWPITCH + lqoff]; // next iter ky0 base

        // -- issue long-latency loads up front: staged row + pc row --
        float st0_v[8], st1_v[8], st2_v[8], st3_v[8], st4_v[8];
        if (yy < 3) {
            IST_LOAD(st0, 0) IST_LOAD(st1, 1) IST_LOAD(st2, 2)
            IST_LOAD(st3, 3) IST_LOAD(st4, 4)
        }
        const int y = y0 + yy;
        float pcv[4][4];
#pragma unroll
        for (int nt = 0; nt < 4; ++nt) {
            const int px = x0 + (nt << 4) + l15;
#pragma unroll
            for (int r = 0; r < 4; ++r) {
                const int c = wave * 16 + quad * 4 + r;
                pcv[nt][r] = pc[((b * 64 + c) * 128 + y) * 128 + px];
            }
        }

        float4v acc[4][4];
#pragma unroll
        for (int mt = 0; mt < 4; ++mt)
#pragma unroll
            for (int nt = 0; nt < 4; ++nt)
                acc[mt][nt] = (float4v){0.f, 0.f, 0.f, 0.f};

        // ---- K-loop over ring slots (yy-1, yy, yy+1)&3; A+B dbuf one step ahead;
        //      last step wraps A to step 0 and B to next iteration's base ----
#pragma unroll 1
        for (int ky = 0; ky < 3; ++ky) {
            const int scur = (yy + ky + 3) & 3;
            const int snxt = (yy + ky) & 3;
            const int dj = (snxt - scur) * 66 - 2;   // slot jump - 2 px rewind
#pragma unroll 1
            for (int kx = 0; kx < 3; ++kx) {
                const bool lastkx = (ky == 2) & (kx == 2);
                const short* bbn = bb + ((kx == 2) ? dj * PST : PST);
#pragma unroll
                for (int kc = 0; kc < 4; ++kc) {
                    const int cur = kc & 1, nxt = cur ^ 1;
                    const bool last = lastkx & (kc == 3);

                    const short* apn = last ? ap_base : (ap + 8192);
#pragma unroll
                    for (int mt = 0; mt < 4; ++mt)
                        abuf[nxt][mt] = *(const short8*)(apn + mt * 512);
                    ap = apn;

                    const short* bq = (kc == 3) ? (lastkx ? bbnext : bbn) : bb;
                    const int kcn = (kc + 1) & 3;
#pragma unroll
                    for (int nt = 0; nt < 4; ++nt) {
                        const short* bp = bq + nt * (16 * PST) + kcn * 32;
                        short4v lo = *(const short4v*)bp;
                        short4v hi = *(const short4v*)(bp + 4);
                        bfr[nxt][nt] = __builtin_shufflevector(lo, hi, 0, 1, 2, 3, 4, 5, 6, 7);
                    }

                    __builtin_amdgcn_s_setprio(1);
#pragma unroll
                    for (int mt = 0; mt < 4; ++mt)
#pragma unroll
                        for (int nt = 0; nt < 4; ++nt)
                            acc[mt][nt] = __builtin_amdgcn_mfma_f32_16x16x32_bf16(
                                abuf[cur][mt], bfr[cur][nt], acc[mt][nt], 0, 0, 0);
                    __builtin_amdgcn_s_setprio(0);
                }
                bb = bbn;
            }
        }
        bb = bbnext;   // reset for next iteration (bfr[0] already wrapped)

        // -- convert + write staged row into ring slot, then publish --
        if (yy < 3) {
            IST_WRITE(st0, 0) IST_WRITE(st1, 1) IST_WRITE(st2, 2)
            IST_WRITE(st3, 3) IST_WRITE(st4, 4)
        }
        __syncthreads();

        // -- epilogue row y (stores drift under next iteration's K-loop) --
#pragma unroll
        for (int nt = 0; nt < 4; ++nt) {
            const int px = x0 + (nt << 4) + l15;
#pragma unroll
            for (int r = 0; r < 4; ++r) {
                const int c = wave * 16 + quad * 4 + r;
                const float gi = acc[0][nt][r] + bgv[0][r];
                const float gf = acc[1][nt][r] + bgv[1][r];
                const float go = acc[2][nt][r] + bgv[2][r];
                const float gc = acc[3][nt][r] + bgv[3][r];
                const float ig = sigmoidf_(gi);
                const float fg = sigmoidf_(gf);
                const float og = sigmoidf_(go);
                const float cg = tanhf_(gc);
                const int idx = ((b * 64 + c) * 128 + y) * 128 + px;
                const float cell = ig * cg + fg * pcv[nt][r];
                const float hid  = og * tanhf_(cell);
                out[idx] = hid;
                out[NPIX_HID + idx] = cell;
            }
        }
    }
}

extern "C" void kernel_launch(void* const* d_in, const int* in_sizes, int n_in,
                              void* d_out, int out_size, void* d_ws, size_t ws_size,
                              hipStream_t stream) {
    const float* x  = (const float*)d_in[0];
    const float* ph = (const float*)d_in[1];
    const float* pc = (const float*)d_in[2];
    const float* W  = (const float*)d_in[3];
    const float* bg = (const float*)d_in[4];
    float* out = (float*)d_out;
    short* aprep = (short*)d_ws;   // 9*16*256*8 bf16 = 589,824 B

    wprep<<<1152, 256, 0, stream>>>(W, aprep);
    convlstm_main<<<512, 256, 0, stream>>>(x, ph, pc, aprep, bg, out);
}

// Round 10
// 207.055 us; speedup vs baseline: 1.2786x; 1.2786x over previous
//
#include <hip/hip_runtime.h>

typedef __attribute__((ext_vector_type(8))) short short8;
typedef __attribute__((ext_vector_type(4))) short short4v;
typedef __attribute__((ext_vector_type(4))) float float4v;

#define NPIX_HID 8388608   // 8*64*128*128
#define PST 132            // shorts per px row in LDS (pitch 66 dwords: measured 0 conflicts w/ b64)

__device__ __forceinline__ short f2bf(float f) {
    union { float f; unsigned u; } v; v.f = f;
    unsigned r = (v.u + 0x7FFFu + ((v.u >> 16) & 1u)) >> 16;
    return (short)r;
}

__device__ __forceinline__ float sigmoidf_(float v) { return 1.f / (1.f + __expf(-v)); }
__device__ __forceinline__ float tanhf_(float v)    { return 2.f / (1.f + __expf(-2.f * v)) - 1.f; }

// Pack W[co][ci][ky][kx] fp32 -> Aprep[kk][ci/8][co][ci%8] bf16 (MFMA A-frag order).
__global__ void wprep(const float* __restrict__ W, short* __restrict__ A) {
    int tid = blockIdx.x * 256 + threadIdx.x;
    if (tid >= 9 * 16 * 256 * 8) return;
    int j   = tid & 7;
    int co  = (tid >> 3) & 255;
    int cig = (tid >> 11) & 15;
    int kk  = tid >> 15;
    int ci  = cig * 8 + j;
    A[tid] = f2bf(W[co * 1152 + ci * 9 + kk]);
}

// Staging load: branchless (clamped addr + select) so batches pipeline.
#define ST_LOAD(P, II)                                                        \
  {                                                                           \
    const int i_ = (II);                                                      \
    P##_act = (i_ < 4224);                                                    \
    const int px_ = i_ % 66;                                                  \
    const int ro_ = i_ / 66;                                                  \
    P##_oct = ro_ & 15;                                                       \
    P##_row = ro_ >> 4;                                                       \
    const int ys_ = y0 + P##_row - 1;                                         \
    const int xs_ = x0 + px_ - 1;                                             \
    P##_px = px_;                                                             \
    P##_ok = P##_act & ((unsigned)ys_ < 128u) & ((unsigned)xs_ < 128u);       \
    const float* src_ = (P##_oct < 8) ? x : ph;                               \
    const float* sp_ = src_ + (P##_ok ?                                       \
        (((b * 64 + (P##_oct & 7) * 8) * 128 + ys_) * 128 + xs_) : 0);        \
    P##_v[0] = sp_[0];        P##_v[1] = sp_[16384];                          \
    P##_v[2] = sp_[2 * 16384]; P##_v[3] = sp_[3 * 16384];                     \
    P##_v[4] = sp_[4 * 16384]; P##_v[5] = sp_[5 * 16384];                     \
    P##_v[6] = sp_[6 * 16384]; P##_v[7] = sp_[7 * 16384];                     \
  }

#define ST_PROC(P)                                                            \
  if (P##_act) {                                                              \
    short4v lo_ = {0,0,0,0}, hi_ = {0,0,0,0};                                 \
    if (P##_ok) {                                                             \
      lo_[0] = f2bf(P##_v[0]); lo_[1] = f2bf(P##_v[1]);                       \
      lo_[2] = f2bf(P##_v[2]); lo_[3] = f2bf(P##_v[3]);                       \
      hi_[0] = f2bf(P##_v[4]); hi_[1] = f2bf(P##_v[5]);                       \
      hi_[2] = f2bf(P##_v[6]); hi_[3] = f2bf(P##_v[7]);                       \
    }                                                                         \
    short* dst_ = &Bs[(P##_row * 66 + P##_px) * PST + P##_oct * 8];           \
    *(short4v*)dst_       = lo_;                                              \
    *(short4v*)(dst_ + 4) = hi_;                                              \
  }

// 2-row tile (proven R7 structure) + XCD-chunked block swizzle: y-adjacent
// tiles share 3/4 halo rows; putting them on the same XCD turns staging
// re-reads into L2 hits. 1024 blocks = 8 XCDs x 128, exactly bijective.
__global__ __launch_bounds__(256, 2) void convlstm_main(
    const float* __restrict__ x, const float* __restrict__ ph,
    const float* __restrict__ pc, const short* __restrict__ aprep,
    const float* __restrict__ bg, float* __restrict__ out)
{
    // Bs[halo row 0..3][px 0..65][ci 0..127], px pitch PST shorts -> 69696 B, 2 blocks/CU
    __shared__ short Bs[4 * 66 * PST];

    const int tid  = threadIdx.x;
    const int lane = tid & 63;
    const int wave = tid >> 6;
    const int l15  = lane & 15;
    const int quad = lane >> 4;

    // XCD-aware swizzle: HW assigns blockIdx round-robin to XCDs (bid%8);
    // map so each XCD owns a contiguous 128-tile chunk (same batch, adjacent y).
    const int t  = (blockIdx.x & 7) * 128 + (blockIdx.x >> 3);
    const int x0 = (t & 1) * 64;
    const int y0 = ((t >> 1) & 63) * 2;
    const int b  = t >> 7;

    // ---- stage 4 halo rows x 66 px x 128 ci; 2-deep rotated load pipeline ----
    {
        float stA_v[8]; int stA_px, stA_row, stA_oct; bool stA_ok, stA_act;
        float stB_v[8]; int stB_px, stB_row, stB_oct; bool stB_ok, stB_act;
        int ib = tid;
        ST_LOAD(stA, ib);
#pragma unroll 1
        for (int it = 0; it < 16; it += 2) {
            ST_LOAD(stB, ib + 256);     // next iter's loads in flight
            ST_PROC(stA);
            ST_LOAD(stA, ib + 512);     // iter after that
            ST_PROC(stB);
            ib += 512;
        }
        ST_PROC(stA);                   // tail iter 16 (i = tid + 4096, act-guarded)
    }
    __syncthreads();

    float4v acc[4][8];
#pragma unroll
    for (int mt = 0; mt < 4; ++mt)
#pragma unroll
        for (int nt = 0; nt < 8; ++nt)
            acc[mt][nt] = (float4v){0.f, 0.f, 0.f, 0.f};

    // ---- K-loop: (ky,kx) unroll-1; kc unrolled; A AND B double-buffered one
    //      kc-step ahead (B prefetch crosses kx/ky boundaries) ----
    const short* ap = aprep + quad * 2048 + (wave * 16 + l15) * 8;   // + step*8192 + mt*512
    short8 abuf[2][4];
#pragma unroll
    for (int mt = 0; mt < 4; ++mt) abuf[0][mt] = *(const short8*)(ap + mt * 512);

    const short* bb = &Bs[l15 * PST + quad * 8];
    short8 bfr[2][8];
#pragma unroll
    for (int nt = 0; nt < 8; ++nt) {
        const short* bp = bb + (nt >> 2) * (66 * PST) + (nt & 3) * (16 * PST);
        short4v lo = *(const short4v*)bp;
        short4v hi = *(const short4v*)(bp + 4);
        bfr[0][nt] = __builtin_shufflevector(lo, hi, 0, 1, 2, 3, 4, 5, 6, 7);
    }

#pragma unroll 1
    for (int ky = 0; ky < 3; ++ky) {
#pragma unroll 1
        for (int kx = 0; kx < 3; ++kx) {
            const bool lastkx = (ky == 2) & (kx == 2);
            // kx+1: px window shifts 1; after kx=2: -2 px + 1 halo row = +64*PST
            const short* bbn = bb + ((kx == 2) ? 64 * PST : PST);
#pragma unroll
            for (int kc = 0; kc < 4; ++kc) {
                const int cur = kc & 1, nxt = cur ^ 1;
                const bool last = lastkx & (kc == 3);

                // A prefetch for next kc-step (reload current on very last step)
                const short* apn = last ? ap : (ap + 8192);
#pragma unroll
                for (int mt = 0; mt < 4; ++mt)
                    abuf[nxt][mt] = *(const short8*)(apn + mt * 512);
                ap = apn;

                // B prefetch for next kc-step (cross kx/ky boundary via bbn)
                const short* bq = (kc == 3) ? (lastkx ? bb : bbn) : bb;
                const int kcn = (kc + 1) & 3;
#pragma unroll
                for (int nt = 0; nt < 8; ++nt) {
                    const short* bp = bq + (nt >> 2) * (66 * PST) + (nt & 3) * (16 * PST) + kcn * 32;
                    short4v lo = *(const short4v*)bp;
                    short4v hi = *(const short4v*)(bp + 4);
                    bfr[nxt][nt] = __builtin_shufflevector(lo, hi, 0, 1, 2, 3, 4, 5, 6, 7);
                }

                // MFMA on current buffers (no in-loop barriers -> phase diversity;
                // setprio keeps the matrix pipe fed)
                __builtin_amdgcn_s_setprio(1);
#pragma unroll
                for (int mt = 0; mt < 4; ++mt)
#pragma unroll
                    for (int nt = 0; nt < 8; ++nt)
                        acc[mt][nt] = __builtin_amdgcn_mfma_f32_16x16x32_bf16(
                            abuf[cur][mt], bfr[cur][nt], acc[mt][nt], 0, 0, 0);
                __builtin_amdgcn_s_setprio(0);
            }
            bb = bbn;
        }
    }

    // ---- fused gating epilogue; pc loads hoisted ahead of all gating math ----
    float pcv[8][4];
#pragma unroll
    for (int nt = 0; nt < 8; ++nt) {
        const int y  = y0 + (nt >> 2);
        const int px = x0 + ((nt & 3) << 4) + l15;
#pragma unroll
        for (int r = 0; r < 4; ++r) {
            const int c = wave * 16 + quad * 4 + r;
            pcv[nt][r] = pc[((b * 64 + c) * 128 + y) * 128 + px];
        }
    }
#pragma unroll
    for (int nt = 0; nt < 8; ++nt) {
        const int y  = y0 + (nt >> 2);
        const int px = x0 + ((nt & 3) << 4) + l15;
#pragma unroll
        for (int r = 0; r < 4; ++r) {
            const int c = wave * 16 + quad * 4 + r;
            const float gi = acc[0][nt][r] + bg[c];
            const float gf = acc[1][nt][r] + bg[64 + c];
            const float go = acc[2][nt][r] + bg[128 + c];
            const float gc = acc[3][nt][r] + bg[192 + c];
            const float ig = sigmoidf_(gi);
            const float fg = sigmoidf_(gf);
            const float og = sigmoidf_(go);
            const float cg = tanhf_(gc);
            const int idx = ((b * 64 + c) * 128 + y) * 128 + px;
            const float cell = ig * cg + fg * pcv[nt][r];
            const float hid  = og * tanhf_(cell);
            out[idx] = hid;
            out[NPIX_HID + idx] = cell;
        }
    }
}

extern "C" void kernel_launch(void* const* d_in, const int* in_sizes, int n_in,
                              void* d_out, int out_size, void* d_ws, size_t ws_size,
                              hipStream_t stream) {
    const float* x  = (const float*)d_in[0];
    const float* ph = (const float*)d_in[1];
    const float* pc = (const float*)d_in[2];
    const float* W  = (const float*)d_in[3];
    const float* bg = (const float*)d_in[4];
    float* out = (float*)d_out;
    short* aprep = (short*)d_ws;   // 9*16*256*8 bf16 = 589,824 B

    wprep<<<1152, 256, 0, stream>>>(W, aprep);
    convlstm_main<<<1024, 256, 0, stream>>>(x, ph, pc, aprep, bg, out);
}